// Round 1
// baseline (41.212 us; speedup 1.0000x reference)
//
#include <hip/hip_runtime.h>

#define ORD 16
#define LCH 128           // chunk length
#define PCH 8192          // number of chunks; PCH*LCH = 2^20
#define QT  20            // truncated chunk-scan depth (0.43^20 ~ 5e-8)
#define NN  (PCH*LCH)
#define CPB 8             // chunks per block in k_fix

// ws float layout:
// [0, PCH*ORD)                   d    : per-chunk local end states (y_loc[L-1-i])
// [PCH*ORD, +ORD*LCH)            Vt   : Vt[j*LCH+k] = (a . M^k)[j]
// [.., +QT*256)                  Gmt  : Gmt[m*256 + i*16 + j] = (G^m)[j][i], G = M^LCH

__global__ __launch_bounds__(256) void k_tables(const float* __restrict__ A_w,
                                                float* __restrict__ ws) {
    __shared__ float Ma[ORD][ORD];
    __shared__ float Mb[ORD][ORD];
    const int tid = threadIdx.x;
    const int i = tid >> 4, j = tid & 15;
    float* Vt  = ws + PCH * ORD;
    float* Gmt = Vt + ORD * LCH;

    // companion matrix: row 0 = a, subdiagonal identity
    Ma[i][j] = (i == 0) ? A_w[j] : ((j == i - 1) ? 1.f : 0.f);
    __syncthreads();
    // 7 squarings -> M^128
    for (int s = 0; s < 7; ++s) {
        float acc = 0.f;
        #pragma unroll
        for (int k = 0; k < ORD; ++k) acc += Ma[i][k] * Ma[k][j];
        __syncthreads();
        Ma[i][j] = acc;
        __syncthreads();
    }
    // G^0 = I
    Gmt[i * 16 + j] = (i == j) ? 1.f : 0.f;
    Mb[i][j] = Ma[i][j];   // Mb = G^1
    __syncthreads();
    for (int m = 1; m < QT; ++m) {
        Gmt[m * 256 + i * 16 + j] = Mb[j][i];  // store (G^m)[j][i] at [m][i][j]
        float acc = 0.f;
        #pragma unroll
        for (int k = 0; k < ORD; ++k) acc += Mb[i][k] * Ma[k][j];
        __syncthreads();
        Mb[i][j] = acc;
        __syncthreads();
    }
    // V table: v_0 = a, v_{k+1}[j] = v[0]*a[j] + v[j+1]  (16-lane recurrence)
    if (tid < ORD) {
        float aj = A_w[tid];
        float v = aj;
        for (int k = 0; k < LCH; ++k) {
            Vt[tid * LCH + k] = v;
            float v0 = __shfl(v, 0, ORD);
            float vn = __shfl_down(v, 1, ORD);
            v = v0 * aj + ((tid < ORD - 1) ? vn : 0.f);
        }
    }
}

__global__ __launch_bounds__(256) void k_local(const float* __restrict__ u,
                                               const float* __restrict__ A_w,
                                               const float* __restrict__ B_w,
                                               float* __restrict__ out,
                                               float* __restrict__ ws) {
    const int c = blockIdx.x * blockDim.x + threadIdx.x;   // chunk id
    if (c >= PCH) return;
    const int base = c * LCH;
    float a[ORD], b[ORD];
    #pragma unroll
    for (int i = 0; i < ORD; ++i) { a[i] = A_w[i]; b[i] = B_w[i]; }
    float uw[ORD];
    #pragma unroll
    for (int j = 0; j < ORD; ++j) uw[j] = u[base + j];  // u[t..t+15] for t=base
    float yr[ORD];
    #pragma unroll
    for (int i = 0; i < ORD; ++i) yr[i] = 0.f;
    float* d = ws;

    for (int k0 = 0; k0 < LCH; k0 += ORD) {
        #pragma unroll
        for (int kk = 0; kk < ORD; ++kk) {
            const int t = base + k0 + kk;
            // x[t] = sum_s b[15-s] * u[t+s]  (u[t+s] lives in slot (kk+s)&15)
            float x = 0.f;
            #pragma unroll
            for (int s = 0; s < ORD; ++s) x += b[15 - s] * uw[(kk + s) & 15];
            // y[t] = x + sum_i a[i]*y[t-1-i]  (y[m] lives in slot m&15)
            float y = x;
            #pragma unroll
            for (int i = 0; i < ORD; ++i) y += a[i] * yr[(kk - 1 - i) & 15];
            yr[kk] = y;
            out[t] = y;               // local (zero-init) y; corrected by k_fix
            uw[kk] = u[t + ORD];      // slide window: drop u[t], add u[t+16]
        }
    }
    // end state: d[c][i] = y_loc[L-1-i] = yr[15-i]
    #pragma unroll
    for (int i = 0; i < ORD; ++i) d[c * ORD + i] = yr[15 - i];
}

__global__ __launch_bounds__(256) void k_fix(float* __restrict__ out,
                                             const float* __restrict__ ws) {
    __shared__ float sG[QT * 256];            // 20 KB
    __shared__ float sV[ORD * LCH];           // 8 KB
    __shared__ float sd[(CPB + QT - 1) * ORD];
    __shared__ float sS[CPB][ORD];
    const float* d   = ws;
    const float* Vt  = ws + PCH * ORD;
    const float* Gmt = Vt + ORD * LCH;
    const int tid = threadIdx.x;
    const int cb = blockIdx.x * CPB;

    for (int idx = tid; idx < QT * 256; idx += 256) sG[idx] = Gmt[idx];
    for (int idx = tid; idx < ORD * LCH; idx += 256) sV[idx] = Vt[idx];
    // stage d for chunks [cb-QT, cb+CPB-1)
    for (int idx = tid; idx < (CPB + QT - 1) * ORD; idx += 256) {
        const int cpr = cb - QT + (idx >> 4);
        sd[idx] = (cpr >= 0) ? d[cpr * ORD + (idx & 15)] : 0.f;
    }
    __syncthreads();
    // phase A: S_c[j] = sum_m (G^m)[j][.] . d[c-1-m]
    if (tid < CPB * ORD) {
        const int cc = tid >> 4, j = tid & 15;
        float s = 0.f;
        #pragma unroll
        for (int m = 0; m < QT; ++m) {
            const int off = (cc - 1 - m + QT) * ORD;
            #pragma unroll
            for (int i = 0; i < ORD; ++i) s += sG[m * 256 + i * 16 + j] * sd[off + i];
        }
        sS[cc][j] = s;
    }
    __syncthreads();
    // phase B: y[cL+k] = y_loc + V_k . S_c
    const int base = cb * LCH;
    #pragma unroll
    for (int it = 0; it < (CPB * LCH) / 256; ++it) {
        const int o = it * 256 + tid;
        const int cc = o >> 7, k = o & (LCH - 1);
        float y = out[base + o];
        #pragma unroll
        for (int j = 0; j < ORD; ++j) y += sV[j * LCH + k] * sS[cc][j];
        out[base + o] = y;
    }
}

extern "C" void kernel_launch(void* const* d_in, const int* in_sizes, int n_in,
                              void* d_out, int out_size, void* d_ws, size_t ws_size,
                              hipStream_t stream) {
    const float* u = (const float*)d_in[0];
    const float* A = (const float*)d_in[1];
    const float* B = (const float*)d_in[2];
    float* out = (float*)d_out;
    float* ws  = (float*)d_ws;
    k_tables<<<1, 256, 0, stream>>>(A, ws);
    k_local<<<PCH / 256, 256, 0, stream>>>(u, A, B, out, ws);
    k_fix<<<PCH / CPB, 256, 0, stream>>>(out, ws);
}